// Round 17
// baseline (148.355 us; speedup 1.0000x reference)
//
#include <hip/hip_runtime.h>
#include <cstdint>

// DetNet NMS, round 17 = round 16 with the k3 launch failure fixed.
// r16 post-mortem: k3's 133.2 KB static LDS exceeded the per-workgroup
// dispatch cap (proven OK: 89 KB r14, 100.4 KB r15) -> silent launch fail ->
// kept rows never written (absmax 1.008 = max kept |d|). Fix: PCMAX 32->24,
// band = 98304 B, total LDS ~= 100.4 KB = r15-proven. Chunks 24..31 use the
// global-fallback staging path (~3us extra). h_prog spin read made volatile.
// Design (re-audited): 128-wide chunks, 4-word LDS band
//   sband[(128T+r)*4+w] = mask[rank 128T+r][word 2T+w]
// lag-2 helper protocol (register carry covers T-1; helpers cover <= T-2,
// spin need = T-1; r11 eager h_prog publish). Garbage-word safety: hi-half
// word 2T only masks live_lo==0; band words >= ncw only feed carries past
// the loop end; helper backward-garbage lands on consumed sdead words;
// concurrent helper writes are OR-idempotent double-cover.
// k2/k_mask identical to r12 (verified). absmax 0.0 r1-4, 6-9, 11-15.

#define M_TOT 8192
#define NMS_T 0.3f
#define PCMAX 24            // 24*128*4*8 = 98304 B band; total ~100.4 KB LDS

// ws layout (bytes)
#define WS_BOX   65536      // float4[8192]
#define WS_D     196608     // float[40960]
#define WS_VCNT  360448     // u32
#define WS_ZROW  393216     // u64[128] dummy zero row (zeroed by k2)
#define WS_MASK  524288     // u64[8192*128] = 8 MB

typedef unsigned long long u64t;

__device__ __forceinline__ uint32_t desc_key(float sv) {
    uint32_t u = __float_as_uint(sv);
    uint32_t m = (u & 0x80000000u) ? ~u : (u | 0x80000000u);
    return ~m;
}
__device__ __forceinline__ u64t rdl64(u64t v, int sl) {
    unsigned lo = (unsigned)__builtin_amdgcn_readlane((int)(unsigned)v, sl);
    unsigned hi = (unsigned)__builtin_amdgcn_readlane((int)(unsigned)(v >> 32), sl);
    return ((u64t)hi << 32) | lo;
}
__device__ __forceinline__ u64t rdfl64(u64t v) {
    unsigned lo = (unsigned)__builtin_amdgcn_readfirstlane((int)(unsigned)v);
    unsigned hi = (unsigned)__builtin_amdgcn_readfirstlane((int)(unsigned)(v >> 32));
    return ((u64t)hi << 32) | lo;
}

__device__ __forceinline__ void scatter_one(
    int i, int rank, u64t key,
    const float* __restrict__ det, const float* __restrict__ offsets,
    const float* __restrict__ scales,
    float4* __restrict__ boxes_srt, float* __restrict__ d_srt)
{
    uint32_t dkey = (uint32_t)(key >> 16);
    if (dkey >= 0x7FFFFFFFu) return;     // score <= 0: row stays zero
    int g = i >> 10;
    float d0 = __fadd_rn(offsets[g*5+0], __fmul_rn(det[i*5+0], scales[g*5+0]));
    float d1 = __fadd_rn(offsets[g*5+1], __fmul_rn(det[i*5+1], scales[g*5+1]));
    float d2 = __fadd_rn(offsets[g*5+2], __fmul_rn(det[i*5+2], scales[g*5+2]));
    float d3 = __fadd_rn(offsets[g*5+3], __fmul_rn(det[i*5+3], scales[g*5+3]));
    float d4 = __fadd_rn(offsets[g*5+4], __fmul_rn(det[i*5+4], scales[g*5+4]));
    d_srt[rank*5+0] = d0; d_srt[rank*5+1] = d1; d_srt[rank*5+2] = d2;
    d_srt[rank*5+3] = d3; d_srt[rank*5+4] = d4;
    float hw = __fmul_rn(d3, 0.5f), hh = __fmul_rn(d4, 0.5f);
    boxes_srt[rank] = make_float4(__fsub_rn(d1, hw), __fsub_rn(d2, hh),
                                  __fadd_rn(d1, hw), __fadd_rn(d2, hh));
}

__global__ __launch_bounds__(256) void k2_rank(
    const float* __restrict__ det, const float* __restrict__ offsets,
    const float* __restrict__ scales, const float* __restrict__ bounds,
    float4* __restrict__ boxes_srt, float* __restrict__ d_srt,
    unsigned int* __restrict__ vcnt, u64t* __restrict__ zrow,
    float* __restrict__ out)
{
    __shared__ u64t skey[M_TOT];
    __shared__ float soff[40], sscl[40], sbnd[32];
    __shared__ int sTop;
    int t = threadIdx.x;
    int lane = t & 63;
    if (t == 0) sTop = 0;
    if (t < 40) { soff[t] = offsets[t]; sscl[t] = scales[t]; }
    if (t < 32) { sbnd[t] = bounds[t]; }
    if (blockIdx.x == 0 && t < 128) zrow[t] = 0ull;
    __syncthreads();

    #pragma unroll 4
    for (int s = 0; s < 32; ++s) {
        int u = s * 256 + t;
        int g = u >> 10;
        float raw_s = det[u * 5 + 0];
        float cx    = det[u * 5 + 1];
        float cy    = det[u * 5 + 2];
        float score = __fadd_rn(soff[g * 5 + 0], __fmul_rn(raw_s, sscl[g * 5 + 0]));
        bool valid = (cx < sbnd[g*4+1]) && (cx > sbnd[g*4+0]) &&
                     (cy < sbnd[g*4+3]) && (cy > sbnd[g*4+2]);
        float sv = valid ? score : -1.0f;
        uint32_t dk = desc_key(sv);
        bool push = dk < 0x7FFFFFFFu;
        u64t key = ((u64t)dk << 16) | (unsigned)u;
        u64t bal = __ballot(push);
        if (bal) {
            int lw = 0;
            if (lane == 0) lw = atomicAdd(&sTop, __popcll(bal));
            int wbase = __builtin_amdgcn_readfirstlane(lw);
            if (push) {
                int off = __popcll(bal & ((1ull << lane) - 1ull));
                skey[wbase + off] = key;
            }
        }
    }
    __syncthreads();
    int V = sTop;
    int Vpad = (V + 15) & ~15;
    if (t < Vpad - V) skey[V + t] = ~0ull;
    {
        int zb = blockIdx.x * 160;
        for (int z = zb + t; z < zb + 160; z += 256) out[z] = 0.0f;
    }
    __syncthreads();
    if (t == 0) *vcnt = (unsigned)V;

    int grp = t >> 3;
    int jq  = t & 7;
    int i = blockIdx.x * 32 + grp;
    int g = i >> 10;
    float raw_s = det[i * 5 + 0];
    float cx    = det[i * 5 + 1];
    float cy    = det[i * 5 + 2];
    float score = __fadd_rn(soff[g * 5 + 0], __fmul_rn(raw_s, sscl[g * 5 + 0]));
    bool valid = (cx < sbnd[g*4+1]) && (cx > sbnd[g*4+0]) &&
                 (cy < sbnd[g*4+3]) && (cy > sbnd[g*4+2]);
    float sv = valid ? score : -1.0f;
    uint32_t dk = desc_key(sv);
    u64t ki = ((u64t)dk << 16) | (unsigned)i;
    const ulonglong2* skey2 = (const ulonglong2*)skey;
    int c = 0;
    int nit = Vpad >> 4;
    #pragma unroll 4
    for (int it = 0; it < nit; ++it) {
        ulonglong2 kj = skey2[it * 8 + jq];
        c += (kj.x < ki) + (kj.y < ki);
    }
    c += __shfl_xor(c, 1);
    c += __shfl_xor(c, 2);
    c += __shfl_xor(c, 4);
    if (jq == 0)
        scatter_one(i, c, ki, det, offsets, scales, boxes_srt, d_srt);
}

// mask build: block (bx,by): rows [bx*32,+32), words [by*16,+16)
__global__ __launch_bounds__(256) void k_mask(
    const float4* __restrict__ boxes_srt,
    const unsigned int* __restrict__ vcnt,
    u64t* __restrict__ mask)
{
    __shared__ float4 sb[16 * 65];
    __shared__ float  sa[16 * 65];
    int V = (int)*vcnt;
    int bx = blockIdx.x, by = blockIdx.y;
    if (bx * 32 >= V) return;
    if (by * 1024 >= V) return;
    if (by * 16 + 15 < (bx * 32) >> 6) return;
    int nc = (V + 63) >> 6;
    int tid = threadIdx.x;
    int cbase = by * 1024;
    for (int u = tid; u < 1024; u += 256) {
        float4 b = boxes_srt[cbase + u];
        int c = u >> 6, jj = u & 63;
        sb[c * 65 + jj] = b;
        sa[c * 65 + jj] = __fmul_rn(fmaxf(__fsub_rn(b.z, b.x), 0.0f),
                                    fmaxf(__fsub_rn(b.w, b.y), 0.0f));
    }
    __syncthreads();
    int r = bx * 32 + (tid >> 3);
    if (r >= V) return;
    float4 bi = boxes_srt[r];
    float ai = __fmul_rn(fmaxf(__fsub_rn(bi.z, bi.x), 0.0f),
                         fmaxf(__fsub_rn(bi.w, bi.y), 0.0f));
    int rw = r >> 6;
    #pragma unroll
    for (int k = 0; k < 2; ++k) {
        int wl = (tid & 7) + k * 8;
        int w = by * 16 + wl;
        if (w < rw || w >= nc) continue;
        u64t bits = 0;
        #pragma unroll 4
        for (int jj = 0; jj < 64; ++jj) {
            float4 bj = sb[wl * 65 + jj];
            float aj = sa[wl * 65 + jj];
            float iw = fmaxf(__fsub_rn(fminf(bi.z, bj.z), fmaxf(bi.x, bj.x)), 0.0f);
            float ih = fmaxf(__fsub_rn(fminf(bi.w, bj.w), fmaxf(bi.y, bj.y)), 0.0f);
            float inter = __fmul_rn(iw, ih);
            float uni   = __fsub_rn(__fadd_rn(ai, aj), inter);
            float iou   = __fdiv_rn(inter, fmaxf(uni, 1e-9f));
            int j = w * 64 + jj;
            if (j > r && iou > NMS_T) bits |= 1ull << jj;
        }
        mask[(size_t)r * 128 + w] = bits;
    }
}

// ---- k3: 128-wide chunks, 4-word band in LDS (PCMAX chunks), lag-2 ----
__global__ __launch_bounds__(512) void k3_serial(
    const u64t* __restrict__ mask, const u64t* __restrict__ zrow,
    const float* __restrict__ d_srt, const unsigned int* __restrict__ vcnt,
    float* __restrict__ out)
{
    __shared__ u64t sband[PCMAX * 128 * 4];  // 98304 B (r15-proven total)
    __shared__ u64t sdead[128];
    __shared__ u64t ck[128];                 // keptmask per 64-word
    __shared__ int  res_prog;
    __shared__ int  h_prog[7];
    int tid = threadIdx.x, wv = tid >> 6, lane = tid & 63;
    int V = (int)*vcnt;
    int nc = (V + 127) >> 7;                 // 128-wide chunks, <= 64
    int PC = min(nc, PCMAX);

    if (tid < 128) {
        int bw = tid * 64;
        u64t w0 = 0;
        if (bw >= V)           w0 = ~0ull;
        else if (bw + 64 > V)  w0 = (~0ull) << (V - bw);
        sdead[tid] = w0;
        ck[tid] = 0ull;
    }
    if (tid == 0) res_prog = 0;
    if (tid < 7)  h_prog[tid] = tid;
    // ---- preload band: words 2c..2c+3 of rank 128c+r (all 8 waves) ----
    for (int e = tid; e < PC * 128; e += 512) {
        int c = e >> 7;                      // chunk; rank = e
        const u64t* rp = mask + (size_t)e * 128;
        ulonglong2 lo = *(const ulonglong2*)(rp + 2 * c);       // 2c,2c+1
        ulonglong2 hi = *(const ulonglong2*)(rp + 2 * c + 2);   // 2c+2,2c+3
        ulonglong2* bp = (ulonglong2*)(sband + (size_t)e * 4);
        bp[0] = lo; bp[1] = hi;
    }
    __syncthreads();

    if (wv == 0) {
        // ---- resolver ----
        u64t cA_lo = 0, cA_hi = 0;           // carries into T from keeps @T-1
        for (int T = 0; T < nc; ++T) {
            // stage diag+carry pairs for rows 128T+lane / 128T+64+lane
            ulonglong2 bl, bln, bh, bhn;
            if (T < PC) {
                const ulonglong2* p0 = (const ulonglong2*)(sband + (size_t)(T * 128 + lane) * 4);
                const ulonglong2* p1 = (const ulonglong2*)(sband + (size_t)(T * 128 + 64 + lane) * 4);
                bl = p0[0]; bln = p0[1];
                bh = p1[0]; bhn = p1[1];
            } else {                          // tail chunks >= PCMAX: global
                int rl = min(T * 128 + lane,      M_TOT - 1);
                int rh = min(T * 128 + 64 + lane, M_TOT - 1);
                int w = min(2 * T, 124);
                const u64t* rpl = mask + (size_t)rl * 128;
                const u64t* rph = mask + (size_t)rh * 128;
                bl  = *(const ulonglong2*)(rpl + w);
                bln = *(const ulonglong2*)(rpl + w + 2);
                bh  = *(const ulonglong2*)(rph + w);
                bhn = *(const ulonglong2*)(rph + w + 2);
            }
            // spin until all chunks <= T-2 applied (lag-2)
            if (T >= 2) {
                int need = T - 1;
                while (true) {
                    int hp = (lane < 7) ? ((volatile int*)h_prog)[lane] : 0x7FFFFFFF;
                    if (__ballot(hp < need) == 0ull) break;
                }
            }
            u64t dlo = rdfl64(((volatile u64t*)sdead)[2 * T]);
            u64t dhi = rdfl64(((volatile u64t*)sdead)[2 * T + 1]);
            u64t live_lo = ~(dlo | cA_lo);
            u64t live_hi = ~(dhi | cA_hi);
            int rem = V - T * 128;
            if (rem < 128) {
                live_lo &= (rem >= 64) ? ~0ull : ((rem <= 0) ? 0ull : ((1ull << rem) - 1ull));
                int rh = rem - 64;
                live_hi &= (rh >= 64) ? ~0ull : ((rh <= 0) ? 0ull : ((1ull << rh) - 1ull));
            }
            u64t km_lo = 0, km_hi = 0;
            while (live_lo) {                 // SALU + readlane per keep
                int bs = (int)__builtin_ctzll(live_lo);
                km_lo |= 1ull << bs;
                u64t rml = rdl64(bl.x, bs);
                u64t rmh = rdl64(bl.y, bs);
                live_lo &= ~rml & ~(1ull << bs);
                live_hi &= ~rmh;
            }
            while (live_hi) {
                int bs = (int)__builtin_ctzll(live_hi);
                km_hi |= 1ull << bs;
                u64t rmh = rdl64(bh.y, bs);   // bh.x garbage-safe: live_lo==0
                live_hi &= ~rmh & ~(1ull << bs);
            }
            if (lane == 0) { ck[2 * T] = km_lo; ck[2 * T + 1] = km_hi; }
            __threadfence_block();
            if (lane == 0) *(volatile int*)&res_prog = T + 1;
            // carries into chunk T+1 (words 2T+2, 2T+3) — off per-keep chain
            u64t c1l = 0, c1h = 0, km = km_lo;
            while (km) {
                int b = (int)__builtin_ctzll(km); km &= km - 1;
                c1l |= rdl64(bln.x, b); c1h |= rdl64(bln.y, b);
            }
            km = km_hi;
            while (km) {
                int b = (int)__builtin_ctzll(km); km &= km - 1;
                c1l |= rdl64(bhn.x, b); c1h |= rdl64(bhn.y, b);
            }
            cA_lo = c1l; cA_hi = c1h;
        }
    } else {
        // ---- helper (wv-1): chunks c == wv-1 (mod 7); full-row ORs ----
        int hh = wv - 1;
        for (int c = hh; c < nc; c += 7) {
            while (*(volatile int*)&res_prog <= c) __builtin_amdgcn_s_sleep(1);
            u64t kl = ((volatile u64t*)ck)[2 * c];
            u64t kh = ((volatile u64t*)ck)[2 * c + 1];
            if (kl | kh) {
                int base = c * 128;
                u64t ax = 0, ay = 0;
                while (kl | kh) {
                    ulonglong2 b[4];
                    #pragma unroll
                    for (int q = 0; q < 4; ++q) {   // 4-slot dummy-padded batch
                        const ulonglong2* ptr;
                        if (kl) {
                            int b_ = __builtin_ctzll(kl); kl &= kl - 1;
                            ptr = (const ulonglong2*)(mask + (size_t)(base + b_) * 128) + lane;
                        } else if (kh) {
                            int b_ = __builtin_ctzll(kh); kh &= kh - 1;
                            ptr = (const ulonglong2*)(mask + (size_t)(base + 64 + b_) * 128) + lane;
                        } else {
                            ptr = (const ulonglong2*)zrow + lane;
                        }
                        b[q] = *ptr;
                    }
                    ax |= b[0].x | b[1].x | b[2].x | b[3].x;
                    ay |= b[0].y | b[1].y | b[2].y | b[3].y;
                }
                atomicOr(&sdead[2 * lane],     ax);
                atomicOr(&sdead[2 * lane + 1], ay);
            }
            __threadfence_block();
            if (lane == 0) ((volatile int*)h_prog)[hh] = c + 7;   // eager publish
        }
        if (lane == 0) ((volatile int*)h_prog)[hh] = 0x7FFFFFFF;
    }
    __syncthreads();
    // output: expand keptmasks
    if (tid < 128) {
        u64t m = ck[tid];
        while (m) {
            int b = __builtin_ctzll(m); m &= m - 1;
            int rr = tid * 64 + b;
            out[rr * 5 + 0] = d_srt[rr * 5 + 0];
            out[rr * 5 + 1] = d_srt[rr * 5 + 1];
            out[rr * 5 + 2] = d_srt[rr * 5 + 2];
            out[rr * 5 + 3] = d_srt[rr * 5 + 3];
            out[rr * 5 + 4] = d_srt[rr * 5 + 4];
        }
    }
}

extern "C" void kernel_launch(void* const* d_in, const int* in_sizes, int n_in,
                              void* d_out, int out_size, void* d_ws, size_t ws_size,
                              hipStream_t stream) {
    const float* det     = (const float*)d_in[0];
    const float* offsets = (const float*)d_in[1];
    const float* scales  = (const float*)d_in[2];
    const float* bounds  = (const float*)d_in[3];
    float* out = (float*)d_out;
    char* ws = (char*)d_ws;
    float4*       boxes = (float4*)(ws + WS_BOX);
    float*        d_srt = (float*)(ws + WS_D);
    unsigned int* vcnt  = (unsigned int*)(ws + WS_VCNT);
    u64t*         zrow  = (u64t*)(ws + WS_ZROW);
    u64t*         mask  = (u64t*)(ws + WS_MASK);

    k2_rank<<<256, 256, 0, stream>>>(det, offsets, scales, bounds, boxes, d_srt, vcnt, zrow, out);
    k_mask<<<dim3(256, 8), 256, 0, stream>>>(boxes, vcnt, mask);
    k3_serial<<<1, 512, 0, stream>>>(mask, zrow, d_srt, vcnt, out);
}

// Round 18
// 139.099 us; speedup vs baseline: 1.0665x; 1.0665x over previous
//
#include <hip/hip_runtime.h>
#include <cstdint>

// DetNet NMS, round 18. r17 accounting: k2+k_mask+k3 ~= 95-100us, each <40
// (hidden under the 40us harness fill in top-5). k3 redesigns are null since
// r15 => attack the never-re-measured k2/k_mask latency exposure:
//   K2: 128 blocks x 512 threads (8 waves -> 2/SIMD): build 16 iters (was
//       32), scan 64 groups/block. Same math, doubled latency hiding.
//   K_MASK: finer tiles 32 rows x 8 words, grid (256,16), 1 word/thread
//       (64 IoUs, was 128); ~2x active blocks; LDS 10.4 KB.
//   K3: identical to r17 (verified; 128-wide chunks, 4-word LDS band 98KB,
//       lag-2 producer/consumer).
// All decision-critical FP math __f*_rn in exact ref op order (absmax 0.0
// r1-4, 6-9, 11-15, 17).

#define M_TOT 8192
#define NMS_T 0.3f
#define PCMAX 24            // 24*128*4*8 = 98304 B band (launch-proven size)

// ws layout (bytes)
#define WS_BOX   65536      // float4[8192]
#define WS_D     196608     // float[40960]
#define WS_VCNT  360448     // u32
#define WS_ZROW  393216     // u64[128] dummy zero row (zeroed by k2)
#define WS_MASK  524288     // u64[8192*128] = 8 MB

typedef unsigned long long u64t;

__device__ __forceinline__ uint32_t desc_key(float sv) {
    uint32_t u = __float_as_uint(sv);
    uint32_t m = (u & 0x80000000u) ? ~u : (u | 0x80000000u);
    return ~m;
}
__device__ __forceinline__ u64t rdl64(u64t v, int sl) {
    unsigned lo = (unsigned)__builtin_amdgcn_readlane((int)(unsigned)v, sl);
    unsigned hi = (unsigned)__builtin_amdgcn_readlane((int)(unsigned)(v >> 32), sl);
    return ((u64t)hi << 32) | lo;
}
__device__ __forceinline__ u64t rdfl64(u64t v) {
    unsigned lo = (unsigned)__builtin_amdgcn_readfirstlane((int)(unsigned)v);
    unsigned hi = (unsigned)__builtin_amdgcn_readfirstlane((int)(unsigned)(v >> 32));
    return ((u64t)hi << 32) | lo;
}

__device__ __forceinline__ void scatter_one(
    int i, int rank, u64t key,
    const float* __restrict__ det, const float* __restrict__ offsets,
    const float* __restrict__ scales,
    float4* __restrict__ boxes_srt, float* __restrict__ d_srt)
{
    uint32_t dkey = (uint32_t)(key >> 16);
    if (dkey >= 0x7FFFFFFFu) return;     // score <= 0: row stays zero
    int g = i >> 10;
    float d0 = __fadd_rn(offsets[g*5+0], __fmul_rn(det[i*5+0], scales[g*5+0]));
    float d1 = __fadd_rn(offsets[g*5+1], __fmul_rn(det[i*5+1], scales[g*5+1]));
    float d2 = __fadd_rn(offsets[g*5+2], __fmul_rn(det[i*5+2], scales[g*5+2]));
    float d3 = __fadd_rn(offsets[g*5+3], __fmul_rn(det[i*5+3], scales[g*5+3]));
    float d4 = __fadd_rn(offsets[g*5+4], __fmul_rn(det[i*5+4], scales[g*5+4]));
    d_srt[rank*5+0] = d0; d_srt[rank*5+1] = d1; d_srt[rank*5+2] = d2;
    d_srt[rank*5+3] = d3; d_srt[rank*5+4] = d4;
    float hw = __fmul_rn(d3, 0.5f), hh = __fmul_rn(d4, 0.5f);
    boxes_srt[rank] = make_float4(__fsub_rn(d1, hw), __fsub_rn(d2, hh),
                                  __fadd_rn(d1, hw), __fadd_rn(d2, hh));
}

// 128 blocks x 512 threads: 8 waves/block = 2/SIMD on active CUs
__global__ __launch_bounds__(512) void k2_rank(
    const float* __restrict__ det, const float* __restrict__ offsets,
    const float* __restrict__ scales, const float* __restrict__ bounds,
    float4* __restrict__ boxes_srt, float* __restrict__ d_srt,
    unsigned int* __restrict__ vcnt, u64t* __restrict__ zrow,
    float* __restrict__ out)
{
    __shared__ u64t skey[M_TOT];
    __shared__ float soff[40], sscl[40], sbnd[32];
    __shared__ int sTop;
    int t = threadIdx.x;
    int lane = t & 63;
    if (t == 0) sTop = 0;
    if (t < 40) { soff[t] = offsets[t]; sscl[t] = scales[t]; }
    if (t < 32) { sbnd[t] = bounds[t]; }
    if (blockIdx.x == 0 && t < 128) zrow[t] = 0ull;
    __syncthreads();

    #pragma unroll 4
    for (int s = 0; s < 16; ++s) {
        int u = s * 512 + t;
        int g = u >> 10;
        float raw_s = det[u * 5 + 0];
        float cx    = det[u * 5 + 1];
        float cy    = det[u * 5 + 2];
        float score = __fadd_rn(soff[g * 5 + 0], __fmul_rn(raw_s, sscl[g * 5 + 0]));
        bool valid = (cx < sbnd[g*4+1]) && (cx > sbnd[g*4+0]) &&
                     (cy < sbnd[g*4+3]) && (cy > sbnd[g*4+2]);
        float sv = valid ? score : -1.0f;
        uint32_t dk = desc_key(sv);
        bool push = dk < 0x7FFFFFFFu;
        u64t key = ((u64t)dk << 16) | (unsigned)u;
        u64t bal = __ballot(push);
        if (bal) {
            int lw = 0;
            if (lane == 0) lw = atomicAdd(&sTop, __popcll(bal));
            int wbase = __builtin_amdgcn_readfirstlane(lw);
            if (push) {
                int off = __popcll(bal & ((1ull << lane) - 1ull));
                skey[wbase + off] = key;
            }
        }
    }
    __syncthreads();
    int V = sTop;
    int Vpad = (V + 15) & ~15;
    if (t < Vpad - V) skey[V + t] = ~0ull;
    {
        int zb = blockIdx.x * 320;       // 128 blocks x 320 = 40960
        for (int z = zb + t; z < zb + 320; z += 512) out[z] = 0.0f;
    }
    __syncthreads();
    if (t == 0) *vcnt = (unsigned)V;

    int grp = t >> 3;                    // 0..63
    int jq  = t & 7;
    int i = blockIdx.x * 64 + grp;       // 128*64 = 8192
    int g = i >> 10;
    float raw_s = det[i * 5 + 0];
    float cx    = det[i * 5 + 1];
    float cy    = det[i * 5 + 2];
    float score = __fadd_rn(soff[g * 5 + 0], __fmul_rn(raw_s, sscl[g * 5 + 0]));
    bool valid = (cx < sbnd[g*4+1]) && (cx > sbnd[g*4+0]) &&
                 (cy < sbnd[g*4+3]) && (cy > sbnd[g*4+2]);
    float sv = valid ? score : -1.0f;
    uint32_t dk = desc_key(sv);
    u64t ki = ((u64t)dk << 16) | (unsigned)i;
    const ulonglong2* skey2 = (const ulonglong2*)skey;
    int c = 0;
    int nit = Vpad >> 4;
    #pragma unroll 4
    for (int it = 0; it < nit; ++it) {
        ulonglong2 kj = skey2[it * 8 + jq];
        c += (kj.x < ki) + (kj.y < ki);
    }
    c += __shfl_xor(c, 1);
    c += __shfl_xor(c, 2);
    c += __shfl_xor(c, 4);
    if (jq == 0)
        scatter_one(i, c, ki, det, offsets, scales, boxes_srt, d_srt);
}

// mask build: block (bx,by): rows [bx*32,+32), words [by*8,+8); 1 word/thread
__global__ __launch_bounds__(256) void k_mask(
    const float4* __restrict__ boxes_srt,
    const unsigned int* __restrict__ vcnt,
    u64t* __restrict__ mask)
{
    __shared__ float4 sb[8 * 65];
    __shared__ float  sa[8 * 65];
    int V = (int)*vcnt;
    int bx = blockIdx.x, by = blockIdx.y;
    if (bx * 32 >= V) return;
    if (by * 512 >= V) return;
    if (by * 8 + 7 < (bx * 32) >> 6) return;   // fully below diagonal
    int nc = (V + 63) >> 6;
    int tid = threadIdx.x;
    int cbase = by * 512;
    for (int u = tid; u < 512; u += 256) {
        float4 b = boxes_srt[cbase + u];
        int c = u >> 6, jj = u & 63;
        sb[c * 65 + jj] = b;
        sa[c * 65 + jj] = __fmul_rn(fmaxf(__fsub_rn(b.z, b.x), 0.0f),
                                    fmaxf(__fsub_rn(b.w, b.y), 0.0f));
    }
    __syncthreads();
    int r = bx * 32 + (tid >> 3);
    if (r >= V) return;
    float4 bi = boxes_srt[r];
    float ai = __fmul_rn(fmaxf(__fsub_rn(bi.z, bi.x), 0.0f),
                         fmaxf(__fsub_rn(bi.w, bi.y), 0.0f));
    int rw = r >> 6;
    int wl = tid & 7;
    int w = by * 8 + wl;
    if (w < rw || w >= nc) return;
    u64t bits = 0;
    #pragma unroll 4
    for (int jj = 0; jj < 64; ++jj) {
        float4 bj = sb[wl * 65 + jj];
        float aj = sa[wl * 65 + jj];
        float iw = fmaxf(__fsub_rn(fminf(bi.z, bj.z), fmaxf(bi.x, bj.x)), 0.0f);
        float ih = fmaxf(__fsub_rn(fminf(bi.w, bj.w), fmaxf(bi.y, bj.y)), 0.0f);
        float inter = __fmul_rn(iw, ih);
        float uni   = __fsub_rn(__fadd_rn(ai, aj), inter);
        float iou   = __fdiv_rn(inter, fmaxf(uni, 1e-9f));
        int j = w * 64 + jj;
        if (j > r && iou > NMS_T) bits |= 1ull << jj;
    }
    mask[(size_t)r * 128 + w] = bits;
}

// ---- k3: 128-wide chunks, 4-word band in LDS (PCMAX chunks), lag-2 ----
__global__ __launch_bounds__(512) void k3_serial(
    const u64t* __restrict__ mask, const u64t* __restrict__ zrow,
    const float* __restrict__ d_srt, const unsigned int* __restrict__ vcnt,
    float* __restrict__ out)
{
    __shared__ u64t sband[PCMAX * 128 * 4];  // 98304 B
    __shared__ u64t sdead[128];
    __shared__ u64t ck[128];                 // keptmask per 64-word
    __shared__ int  res_prog;
    __shared__ int  h_prog[7];
    int tid = threadIdx.x, wv = tid >> 6, lane = tid & 63;
    int V = (int)*vcnt;
    int nc = (V + 127) >> 7;                 // 128-wide chunks, <= 64
    int PC = min(nc, PCMAX);

    if (tid < 128) {
        int bw = tid * 64;
        u64t w0 = 0;
        if (bw >= V)           w0 = ~0ull;
        else if (bw + 64 > V)  w0 = (~0ull) << (V - bw);
        sdead[tid] = w0;
        ck[tid] = 0ull;
    }
    if (tid == 0) res_prog = 0;
    if (tid < 7)  h_prog[tid] = tid;
    for (int e = tid; e < PC * 128; e += 512) {
        int c = e >> 7;
        const u64t* rp = mask + (size_t)e * 128;
        ulonglong2 lo = *(const ulonglong2*)(rp + 2 * c);
        ulonglong2 hi = *(const ulonglong2*)(rp + 2 * c + 2);
        ulonglong2* bp = (ulonglong2*)(sband + (size_t)e * 4);
        bp[0] = lo; bp[1] = hi;
    }
    __syncthreads();

    if (wv == 0) {
        u64t cA_lo = 0, cA_hi = 0;
        for (int T = 0; T < nc; ++T) {
            ulonglong2 bl, bln, bh, bhn;
            if (T < PC) {
                const ulonglong2* p0 = (const ulonglong2*)(sband + (size_t)(T * 128 + lane) * 4);
                const ulonglong2* p1 = (const ulonglong2*)(sband + (size_t)(T * 128 + 64 + lane) * 4);
                bl = p0[0]; bln = p0[1];
                bh = p1[0]; bhn = p1[1];
            } else {
                int rl = min(T * 128 + lane,      M_TOT - 1);
                int rh = min(T * 128 + 64 + lane, M_TOT - 1);
                int w = min(2 * T, 124);
                const u64t* rpl = mask + (size_t)rl * 128;
                const u64t* rph = mask + (size_t)rh * 128;
                bl  = *(const ulonglong2*)(rpl + w);
                bln = *(const ulonglong2*)(rpl + w + 2);
                bh  = *(const ulonglong2*)(rph + w);
                bhn = *(const ulonglong2*)(rph + w + 2);
            }
            if (T >= 2) {
                int need = T - 1;
                while (true) {
                    int hp = (lane < 7) ? ((volatile int*)h_prog)[lane] : 0x7FFFFFFF;
                    if (__ballot(hp < need) == 0ull) break;
                }
            }
            u64t dlo = rdfl64(((volatile u64t*)sdead)[2 * T]);
            u64t dhi = rdfl64(((volatile u64t*)sdead)[2 * T + 1]);
            u64t live_lo = ~(dlo | cA_lo);
            u64t live_hi = ~(dhi | cA_hi);
            int rem = V - T * 128;
            if (rem < 128) {
                live_lo &= (rem >= 64) ? ~0ull : ((rem <= 0) ? 0ull : ((1ull << rem) - 1ull));
                int rh = rem - 64;
                live_hi &= (rh >= 64) ? ~0ull : ((rh <= 0) ? 0ull : ((1ull << rh) - 1ull));
            }
            u64t km_lo = 0, km_hi = 0;
            while (live_lo) {
                int bs = (int)__builtin_ctzll(live_lo);
                km_lo |= 1ull << bs;
                u64t rml = rdl64(bl.x, bs);
                u64t rmh = rdl64(bl.y, bs);
                live_lo &= ~rml & ~(1ull << bs);
                live_hi &= ~rmh;
            }
            while (live_hi) {
                int bs = (int)__builtin_ctzll(live_hi);
                km_hi |= 1ull << bs;
                u64t rmh = rdl64(bh.y, bs);   // bh.x garbage-safe: live_lo==0
                live_hi &= ~rmh & ~(1ull << bs);
            }
            if (lane == 0) { ck[2 * T] = km_lo; ck[2 * T + 1] = km_hi; }
            __threadfence_block();
            if (lane == 0) *(volatile int*)&res_prog = T + 1;
            u64t c1l = 0, c1h = 0, km = km_lo;
            while (km) {
                int b = (int)__builtin_ctzll(km); km &= km - 1;
                c1l |= rdl64(bln.x, b); c1h |= rdl64(bln.y, b);
            }
            km = km_hi;
            while (km) {
                int b = (int)__builtin_ctzll(km); km &= km - 1;
                c1l |= rdl64(bhn.x, b); c1h |= rdl64(bhn.y, b);
            }
            cA_lo = c1l; cA_hi = c1h;
        }
    } else {
        int hh = wv - 1;
        for (int c = hh; c < nc; c += 7) {
            while (*(volatile int*)&res_prog <= c) __builtin_amdgcn_s_sleep(1);
            u64t kl = ((volatile u64t*)ck)[2 * c];
            u64t kh = ((volatile u64t*)ck)[2 * c + 1];
            if (kl | kh) {
                int base = c * 128;
                u64t ax = 0, ay = 0;
                while (kl | kh) {
                    ulonglong2 b[4];
                    #pragma unroll
                    for (int q = 0; q < 4; ++q) {
                        const ulonglong2* ptr;
                        if (kl) {
                            int b_ = __builtin_ctzll(kl); kl &= kl - 1;
                            ptr = (const ulonglong2*)(mask + (size_t)(base + b_) * 128) + lane;
                        } else if (kh) {
                            int b_ = __builtin_ctzll(kh); kh &= kh - 1;
                            ptr = (const ulonglong2*)(mask + (size_t)(base + 64 + b_) * 128) + lane;
                        } else {
                            ptr = (const ulonglong2*)zrow + lane;
                        }
                        b[q] = *ptr;
                    }
                    ax |= b[0].x | b[1].x | b[2].x | b[3].x;
                    ay |= b[0].y | b[1].y | b[2].y | b[3].y;
                }
                atomicOr(&sdead[2 * lane],     ax);
                atomicOr(&sdead[2 * lane + 1], ay);
            }
            __threadfence_block();
            if (lane == 0) ((volatile int*)h_prog)[hh] = c + 7;
        }
        if (lane == 0) ((volatile int*)h_prog)[hh] = 0x7FFFFFFF;
    }
    __syncthreads();
    if (tid < 128) {
        u64t m = ck[tid];
        while (m) {
            int b = __builtin_ctzll(m); m &= m - 1;
            int rr = tid * 64 + b;
            out[rr * 5 + 0] = d_srt[rr * 5 + 0];
            out[rr * 5 + 1] = d_srt[rr * 5 + 1];
            out[rr * 5 + 2] = d_srt[rr * 5 + 2];
            out[rr * 5 + 3] = d_srt[rr * 5 + 3];
            out[rr * 5 + 4] = d_srt[rr * 5 + 4];
        }
    }
}

extern "C" void kernel_launch(void* const* d_in, const int* in_sizes, int n_in,
                              void* d_out, int out_size, void* d_ws, size_t ws_size,
                              hipStream_t stream) {
    const float* det     = (const float*)d_in[0];
    const float* offsets = (const float*)d_in[1];
    const float* scales  = (const float*)d_in[2];
    const float* bounds  = (const float*)d_in[3];
    float* out = (float*)d_out;
    char* ws = (char*)d_ws;
    float4*       boxes = (float4*)(ws + WS_BOX);
    float*        d_srt = (float*)(ws + WS_D);
    unsigned int* vcnt  = (unsigned int*)(ws + WS_VCNT);
    u64t*         zrow  = (u64t*)(ws + WS_ZROW);
    u64t*         mask  = (u64t*)(ws + WS_MASK);

    k2_rank<<<128, 512, 0, stream>>>(det, offsets, scales, bounds, boxes, d_srt, vcnt, zrow, out);
    k_mask<<<dim3(256, 16), 256, 0, stream>>>(boxes, vcnt, mask);
    k3_serial<<<1, 512, 0, stream>>>(mask, zrow, d_srt, vcnt, out);
}